// Round 6
// baseline (37960.535 us; speedup 1.0000x reference)
//
#include <hip/hip_runtime.h>
#include <math.h>

// Problem constants
constexpr int kH   = 64;
constexpr int kP   = 4;
constexpr int kN   = 16;
constexpr int kD   = 8;
constexpr int kT   = 64;
constexpr int kWd  = 512;
constexpr int kB   = 2048;
constexpr int kDIN = 1 + kH + kP * kH;  // 321
constexpr int kKP  = 384;               // K padded to multiple of 64
constexpr int kBH  = kB * kH;           // 131072
constexpr int kNF  = 64 * 5 * 32;       // flag count

typedef __attribute__((ext_vector_type(8))) short short8;
typedef __attribute__((ext_vector_type(4))) float f32x4;

// ---- bf16 helpers -----------------------------------------------------------
__device__ __forceinline__ short f2bf(float x) {
    union { float f; unsigned u; } v; v.f = x;
    unsigned r = (v.u + 0x7FFFu + ((v.u >> 16) & 1u)) >> 16;
    return (short)r;
}
__device__ __forceinline__ float bf2f(short h) {
    union { unsigned u; float f; } v; v.u = ((unsigned)(unsigned short)h) << 16;
    return v.f;
}

// ---- async global->LDS 16B --------------------------------------------------
__device__ __forceinline__ void gload16(const short* g, short* l) {
    __builtin_amdgcn_global_load_lds(
        (const __attribute__((address_space(1))) unsigned int*)g,
        (__attribute__((address_space(3))) unsigned int*)l, 16, 0, 0);
}

// ---- inter-block flag sync (agent scope) ------------------------------------
__device__ __forceinline__ void signal_flag(int* f, int inc) {
    __threadfence();           // release: flush this thread's stores
    __syncthreads();           // all threads' fences done
    if (threadIdx.x == 0)
        __hip_atomic_fetch_add(f, inc, __ATOMIC_RELEASE, __HIP_MEMORY_SCOPE_AGENT);
}
__device__ __forceinline__ void wait_flag(int* f, int target) {
    if (threadIdx.x == 0) {
        while (__hip_atomic_load(f, __ATOMIC_ACQUIRE, __HIP_MEMORY_SCOPE_AGENT) < target)
            __builtin_amdgcn_s_sleep(2);
    }
    __syncthreads();
    __threadfence();           // acquire: invalidate stale cache lines
}

// ---- weight transpose to bf16 [N][K] with padding ---------------------------
__global__ __launch_bounds__(256) void transpose_bf16(const float* __restrict__ W,
                                                      short* __restrict__ Wt,
                                                      int K, int N, int Kp, int Np) {
    int idx = blockIdx.x * 256 + threadIdx.x;
    if (idx >= Kp * Np) return;
    int n = idx / Kp, kk = idx % Kp;
    float v = (kk < K && n < N) ? W[(size_t)kk * N + n] : 0.f;
    Wt[idx] = f2bf(v);
}

__global__ __launch_bounds__(256) void prep_bias(const float* __restrict__ fb0,
                                                 const float* __restrict__ gb0,
                                                 float* __restrict__ b0c) {
    int i = blockIdx.x * 256 + threadIdx.x;
    if (i < 1024) b0c[i] = (i < kWd) ? fb0[i] : gb0[i - kWd];
}

// ---- init: hist[0]=1, tx pad cols zero, flags zero --------------------------
__global__ __launch_bounds__(256) void init_k(float* __restrict__ hist,
                                              short* __restrict__ txh,
                                              int* __restrict__ flags) {
    int idx = blockIdx.x * 256 + threadIdx.x;
    if (idx < kBH) hist[idx] = 1.0f;
    if (idx < kB * (kKP - kDIN)) {
        int b = idx / (kKP - kDIN), c = idx % (kKP - kDIN);
        txh[(size_t)b * kKP + kDIN + c] = 0;
    }
    if (idx < kNF) flags[idx] = 0;
}

// ---- 64x64 MFMA GEMM tile (pointers pre-offset to tile origin) --------------
// mode: 0 = relu->bf16, 1 = tanh->bf16, 2 = tanh->fp32
__device__ __forceinline__ void gemm_tile(const short* __restrict__ A, int lda,
                                          const short* __restrict__ B, int K,
                                          const float* __restrict__ bias, int mode,
                                          short* __restrict__ Cb,
                                          float* __restrict__ Cf, int ldc,
                                          short* sA, short* sB, int tid) {
    const int lane = tid & 63;
    const int w = tid >> 6;
    const int wm = (w & 1) * 32;
    const int wn = (w >> 1) * 32;

    const int sr = tid >> 2;
    const int s  = tid & 3;
    const int scol = (s ^ ((sr >> 1) & 3)) * 8;    // inverse-swizzled source col
    const int sdst = sr * 32 + s * 8;              // linear LDS dest

    const short* gA = A + (size_t)sr * lda + scol;
    const short* gB = B + (size_t)sr * K + scol;

    const int nk = K >> 6;                         // 6 or 8 (always even)
    f32x4 acc[2][2] = {};

    gload16(gA,      sA + sdst);
    gload16(gA + 32, sA + 2048 + sdst);
    gload16(gB,      sB + sdst);
    gload16(gB + 32, sB + 2048 + sdst);

    const int fr = lane & 15;
    const int kb = ((lane >> 4) ^ ((fr >> 1) & 3)) * 8;  // swizzled read col
    const int ra0 = (wm + fr) * 32 + kb, ra1 = (wm + 16 + fr) * 32 + kb;
    const int rb0 = (wn + fr) * 32 + kb, rb1 = (wn + 16 + fr) * 32 + kb;

    for (int kt = 0; kt < nk; ++kt) {
        __syncthreads();  // implicit vmcnt(0): buf staged, prev reads done
        const int cur = (kt & 1) * 4096;
        const int nxt = 4096 - cur;
        if (kt + 1 < nk) {
            const int ko = (kt + 1) << 6;
            gload16(gA + ko,      sA + nxt + sdst);
            gload16(gA + ko + 32, sA + nxt + 2048 + sdst);
            gload16(gB + ko,      sB + nxt + sdst);
            gload16(gB + ko + 32, sB + nxt + 2048 + sdst);
        }
#pragma unroll
        for (int ks = 0; ks < 2; ++ks) {
            short8 a0 = *(const short8*)&sA[cur + ks * 2048 + ra0];
            short8 a1 = *(const short8*)&sA[cur + ks * 2048 + ra1];
            short8 b0 = *(const short8*)&sB[cur + ks * 2048 + rb0];
            short8 b1 = *(const short8*)&sB[cur + ks * 2048 + rb1];
            acc[0][0] = __builtin_amdgcn_mfma_f32_16x16x32_bf16(a0, b0, acc[0][0], 0, 0, 0);
            acc[0][1] = __builtin_amdgcn_mfma_f32_16x16x32_bf16(a0, b1, acc[0][1], 0, 0, 0);
            acc[1][0] = __builtin_amdgcn_mfma_f32_16x16x32_bf16(a1, b0, acc[1][0], 0, 0, 0);
            acc[1][1] = __builtin_amdgcn_mfma_f32_16x16x32_bf16(a1, b1, acc[1][1], 0, 0, 0);
        }
    }

    const int rq = (lane >> 4) * 4;
#pragma unroll
    for (int jj = 0; jj < 2; ++jj) {
        int n = wn + jj * 16 + fr;
        float bv = bias[n];
#pragma unroll
        for (int i = 0; i < 2; ++i) {
#pragma unroll
            for (int r = 0; r < 4; ++r) {
                int m = wm + i * 16 + rq + r;
                float v = acc[i][jj][r] + bv;
                if (mode == 0)      Cb[(size_t)m * ldc + n] = f2bf(fmaxf(v, 0.f));
                else if (mode == 1) Cb[(size_t)m * ldc + n] = f2bf(tanhf(v));
                else                Cf[(size_t)m * ldc + n] = tanhf(v);
            }
        }
    }
}

// ---- persistent mega-kernel: all 63 steps, flag-synced per m-tile -----------
// 512 blocks = 32 m-tiles x 16 n-tiles; XCD decode puts all 16 blocks of an
// m-tile on one XCD (assuming round-robin dispatch). 2 blocks/CU co-resident
// (33 KB LDS, <=128 VGPR) so flag spins cannot deadlock.
__global__ __launch_bounds__(256, 2) void mega(
    float* __restrict__ hist, float* __restrict__ drift,
    short* __restrict__ diffb, short* __restrict__ txh,
    short* __restrict__ b1h, short* __restrict__ b2h,
    const short* __restrict__ W0t, const float* __restrict__ b0c,
    const short* __restrict__ fW1t, const float* __restrict__ fb1,
    const short* __restrict__ gW1t, const float* __restrict__ gb1,
    const short* __restrict__ fW2t, const float* __restrict__ fb2,
    const short* __restrict__ gW2t, const float* __restrict__ gb2,
    const short* __restrict__ fW3t, const float* __restrict__ fb3,
    const short* __restrict__ gW3t, const float* __restrict__ gb3,
    const float* __restrict__ dbt, int* __restrict__ flags) {
    __shared__ __align__(16) short sA[2 * 2 * 2048];
    __shared__ __align__(16) short sB[2 * 2 * 2048];
    __shared__ float ctab[kT * kP];

    const int bid = blockIdx.x;
    const int c = bid & 7, j = bid >> 3;
    const int mt = c + 8 * (j & 3);        // all nt of an mt share an XCD
    const int nt = j >> 2;
    const int m0 = mt * 64;
    const int tid = threadIdx.x;

    for (int k = 0; k < kT; ++k) {
        // ---------- P0: update state + build tx features ----------
        if (k > 0) wait_flag(&flags[((k - 1) * 5 + 4) * 32 + mt], 17);

        {
            const int L = k + 1;
            if (k < kT - 1) {
                float invs = rsqrtf((float)L);
                for (int i = tid; i < L * 4; i += 256) {
                    int jj = i >> 2, pp = i & 3;
                    ctab[i] = cosf(6.283185307179586f * (float)(pp * jj) / (float)L) * invs;
                }
                __syncthreads();
            }
            const int bl = tid >> 6, h = tid & 63;
            const int b = m0 + nt * 4 + bl;
            float xk;
            if (k == 0) {
                xk = 1.0f;
            } else {
                xk = hist[(size_t)(k - 1) * kBH + b * 64 + h] + drift[b * 64 + h];
                const short* dr = diffb + (size_t)b * 1024 + h * kN;
                const float* wr = dbt + (size_t)(k - 1) * kB * kN + b * kN;
#pragma unroll
                for (int n = 0; n < kN; ++n) xk += bf2f(dr[n]) * wr[n];
                hist[(size_t)k * kBH + b * 64 + h] = xk;
            }
            if (k == kT - 1) break;  // final update stored; no more GEMMs

            const float* hp = hist + (size_t)b * 64 + h;
            float a0 = 0.f, a1 = 0.f, a2 = 0.f, a3 = 0.f;
            for (int jj = 0; jj < k; ++jj) {
                float x = hp[(size_t)jj * kBH];
                a0 += x * ctab[jj * 4 + 0];
                a1 += x * ctab[jj * 4 + 1];
                a2 += x * ctab[jj * 4 + 2];
                a3 += x * ctab[jj * 4 + 3];
            }
            a0 += xk * ctab[k * 4 + 0];
            a1 += xk * ctab[k * 4 + 1];
            a2 += xk * ctab[k * 4 + 2];
            a3 += xk * ctab[k * 4 + 3];
            if (L < 2) a1 = 0.f;
            if (L < 4) a2 = 0.f;
            if (L < 6) a3 = 0.f;
            short* th = txh + (size_t)b * kKP;
            th[1 + kH + 0 * kH + h] = f2bf(a0);
            th[1 + kH + 1 * kH + h] = f2bf(a1);
            th[1 + kH + 2 * kH + h] = f2bf(a2);
            th[1 + kH + 3 * kH + h] = f2bf(a3);
            th[1 + h] = f2bf(xk);
            if (h == 0) th[0] = f2bf((float)k);
        }
        signal_flag(&flags[(k * 5 + 0) * 32 + mt], 1);

        // ---------- L1: tx[64x384] @ W0t -> b1 (relu) ----------
        wait_flag(&flags[(k * 5 + 0) * 32 + mt], 16);
        gemm_tile(txh + (size_t)m0 * kKP, kKP, W0t + (size_t)nt * 64 * kKP, kKP,
                  b0c + nt * 64, 0, b1h + (size_t)m0 * 1024 + nt * 64, nullptr, 1024,
                  sA, sB, tid);
        signal_flag(&flags[(k * 5 + 1) * 32 + mt], 1);

        // ---------- L2: b1 -> b2 (relu), f|g halves ----------
        wait_flag(&flags[(k * 5 + 1) * 32 + mt], 16);
        if (nt < 8)
            gemm_tile(b1h + (size_t)m0 * 1024, 1024, fW1t + (size_t)nt * 64 * 512, 512,
                      fb1 + nt * 64, 0, b2h + (size_t)m0 * 1024 + nt * 64, nullptr, 1024,
                      sA, sB, tid);
        else
            gemm_tile(b1h + (size_t)m0 * 1024 + 512, 1024, gW1t + (size_t)(nt - 8) * 64 * 512, 512,
                      gb1 + (nt - 8) * 64, 0, b2h + (size_t)m0 * 1024 + nt * 64, nullptr, 1024,
                      sA, sB, tid);
        signal_flag(&flags[(k * 5 + 2) * 32 + mt], 1);

        // ---------- L3: b2 -> b1 (relu), f|g halves ----------
        wait_flag(&flags[(k * 5 + 2) * 32 + mt], 16);
        if (nt < 8)
            gemm_tile(b2h + (size_t)m0 * 1024, 1024, fW2t + (size_t)nt * 64 * 512, 512,
                      fb2 + nt * 64, 0, b1h + (size_t)m0 * 1024 + nt * 64, nullptr, 1024,
                      sA, sB, tid);
        else
            gemm_tile(b2h + (size_t)m0 * 1024 + 512, 1024, gW2t + (size_t)(nt - 8) * 64 * 512, 512,
                      gb2 + (nt - 8) * 64, 0, b1h + (size_t)m0 * 1024 + nt * 64, nullptr, 1024,
                      sA, sB, tid);
        signal_flag(&flags[(k * 5 + 3) * 32 + mt], 1);

        // ---------- L4: drift (tanh,fp32) by nt==0; diffb (tanh,bf16) by all --
        wait_flag(&flags[(k * 5 + 3) * 32 + mt], 16);
        if (nt == 0)
            gemm_tile(b1h + (size_t)m0 * 1024, 1024, fW3t, 512,
                      fb3, 2, nullptr, drift + (size_t)m0 * 64, 64, sA, sB, tid);
        gemm_tile(b1h + (size_t)m0 * 1024 + 512, 1024, gW3t + (size_t)nt * 64 * 512, 512,
                  gb3 + nt * 64, 1, diffb + (size_t)m0 * 1024 + nt * 64, nullptr, 1024,
                  sA, sB, tid);
        signal_flag(&flags[(k * 5 + 4) * 32 + mt], nt == 0 ? 2 : 1);
    }
}

// ---- readout ----------------------------------------------------------------
__global__ __launch_bounds__(256) void readout_k(const float* __restrict__ hist,
                                                 const float* __restrict__ rW,
                                                 const float* __restrict__ rb,
                                                 const float* __restrict__ ts,
                                                 float* __restrict__ out) {
    __shared__ float sW[kH * kD];
    __shared__ float sb[kD];
    __shared__ float sts[kT];
    int tid = threadIdx.x;
    sW[tid] = rW[tid];
    sW[tid + 256] = rW[tid + 256];
    if (tid < kD) sb[tid] = rb[tid];
    if (tid < kT) sts[tid] = ts[tid];
    __syncthreads();
    int idx = blockIdx.x * 256 + tid;
    int t = idx & (kT - 1), b = idx >> 6;
    const float* xr = hist + (size_t)t * kBH + (size_t)b * kH;
    float acc[kD];
#pragma unroll
    for (int d = 0; d < kD; ++d) acc[d] = sb[d];
    for (int h = 0; h < kH; ++h) {
        float x = xr[h];
#pragma unroll
        for (int d = 0; d < kD; ++d) acc[d] += x * sW[h * kD + d];
    }
    float* o = out + (size_t)((size_t)b * kT + t) * (1 + kD);
    o[0] = sts[t];
#pragma unroll
    for (int d = 0; d < kD; ++d) o[1 + d] = acc[d];
}

extern "C" void kernel_launch(void* const* d_in, const int* in_sizes, int n_in,
                              void* d_out, int out_size, void* d_ws, size_t ws_size,
                              hipStream_t stream) {
    const float* fW0 = (const float*)d_in[0];  const float* fb0 = (const float*)d_in[1];
    const float* fW1 = (const float*)d_in[2];  const float* fb1 = (const float*)d_in[3];
    const float* fW2 = (const float*)d_in[4];  const float* fb2 = (const float*)d_in[5];
    const float* fW3 = (const float*)d_in[6];  const float* fb3 = (const float*)d_in[7];
    const float* gW0 = (const float*)d_in[8];  const float* gb0 = (const float*)d_in[9];
    const float* gW1 = (const float*)d_in[10]; const float* gb1 = (const float*)d_in[11];
    const float* gW2 = (const float*)d_in[12]; const float* gb2 = (const float*)d_in[13];
    const float* gW3 = (const float*)d_in[14]; const float* gb3 = (const float*)d_in[15];
    const float* rW  = (const float*)d_in[16]; const float* rb  = (const float*)d_in[17];
    const float* ts  = (const float*)d_in[18]; const float* dbt = (const float*)d_in[19];
    float* out = (float*)d_out;

    // workspace carve (all 16B aligned). Total ~52 MB.
    char* p = (char*)d_ws;
    float* hist  = (float*)p;  p += (size_t)kT * kBH * 4;     // 33.55 MB
    float* drift = (float*)p;  p += (size_t)kBH * 4;          // 0.52 MB
    float* b0c   = (float*)p;  p += 1024 * 4;
    short* diffb = (short*)p;  p += (size_t)kB * 1024 * 2;    // 4 MB (bf16)
    short* txh   = (short*)p;  p += (size_t)kB * kKP * 2;     // 1.5 MB
    short* b1h   = (short*)p;  p += (size_t)kB * 1024 * 2;    // 4 MB
    short* b2h   = (short*)p;  p += (size_t)kB * 1024 * 2;    // 4 MB
    short* W0t   = (short*)p;  p += (size_t)1024 * kKP * 2;   // 0.75 MB
    short* fW1t  = (short*)p;  p += (size_t)512 * 512 * 2;
    short* gW1t  = (short*)p;  p += (size_t)512 * 512 * 2;
    short* fW2t  = (short*)p;  p += (size_t)512 * 512 * 2;
    short* gW2t  = (short*)p;  p += (size_t)512 * 512 * 2;
    short* fW3t  = (short*)p;  p += (size_t)64 * 512 * 2;
    short* gW3t  = (short*)p;  p += (size_t)1024 * 512 * 2;
    int*   flags = (int*)p;    p += (size_t)kNF * 4;          // 40 KB

    auto tgrid = [](int n) { return dim3((n + 255) / 256); };
    transpose_bf16<<<tgrid(kKP * 512), 256, 0, stream>>>(fW0, W0t, kDIN, 512, kKP, 512);
    transpose_bf16<<<tgrid(kKP * 512), 256, 0, stream>>>(gW0, W0t + (size_t)512 * kKP, kDIN, 512, kKP, 512);
    transpose_bf16<<<tgrid(512 * 512), 256, 0, stream>>>(fW1, fW1t, 512, 512, 512, 512);
    transpose_bf16<<<tgrid(512 * 512), 256, 0, stream>>>(gW1, gW1t, 512, 512, 512, 512);
    transpose_bf16<<<tgrid(512 * 512), 256, 0, stream>>>(fW2, fW2t, 512, 512, 512, 512);
    transpose_bf16<<<tgrid(512 * 512), 256, 0, stream>>>(gW2, gW2t, 512, 512, 512, 512);
    transpose_bf16<<<tgrid(512 * 64), 256, 0, stream>>>(fW3, fW3t, 512, 64, 512, 64);
    transpose_bf16<<<tgrid(512 * 1024), 256, 0, stream>>>(gW3, gW3t, 512, 1024, 512, 1024);
    prep_bias<<<dim3(4), 256, 0, stream>>>(fb0, gb0, b0c);
    init_k<<<dim3(kBH / 256), 256, 0, stream>>>(hist, txh, flags);

    mega<<<dim3(512), 256, 0, stream>>>(hist, drift, diffb, txh, b1h, b2h,
                                        W0t, b0c, fW1t, fb1, gW1t, gb1,
                                        fW2t, fb2, gW2t, gb2, fW3t, fb3, gW3t, gb3,
                                        dbt, flags);

    readout_k<<<dim3(kB * kT / 256), 256, 0, stream>>>(hist, rW, rb, ts, out);
}

// Round 7
// 8585.347 us; speedup vs baseline: 4.4215x; 4.4215x over previous
//
#include <hip/hip_runtime.h>
#include <math.h>

// Problem constants
constexpr int kH   = 64;
constexpr int kP   = 4;
constexpr int kN   = 16;
constexpr int kD   = 8;
constexpr int kT   = 64;
constexpr int kWd  = 512;
constexpr int kB   = 2048;
constexpr int kDIN = 1 + kH + kP * kH;  // 321
constexpr int kKP  = 384;               // K padded to multiple of 64
constexpr int kBH  = kB * kH;           // 131072
constexpr int kNF  = 64 * 5 * 32;       // logical flag count
constexpr int kFS  = 16;                // flag stride (ints) = 64B padding
constexpr int kNFP = kNF * kFS;         // padded flag ints

typedef __attribute__((ext_vector_type(8))) short short8;
typedef __attribute__((ext_vector_type(4))) float f32x4;

// ---- bf16 helpers -----------------------------------------------------------
__device__ __forceinline__ short f2bf(float x) {
    union { float f; unsigned u; } v; v.f = x;
    unsigned r = (v.u + 0x7FFFu + ((v.u >> 16) & 1u)) >> 16;
    return (short)r;
}
__device__ __forceinline__ float bf2f(short h) {
    union { unsigned u; float f; } v; v.u = ((unsigned)(unsigned short)h) << 16;
    return v.f;
}

// ---- async global->LDS 16B --------------------------------------------------
__device__ __forceinline__ void gload16(const short* g, short* l) {
    __builtin_amdgcn_global_load_lds(
        (const __attribute__((address_space(1))) unsigned int*)g,
        (__attribute__((address_space(3))) unsigned int*)l, 16, 0, 0);
}

// ---- inter-block flag sync --------------------------------------------------
// KEY FIX vs round 5: no cache-maintenance op per poll / per thread.
// signal: barrier (drains all threads' stores into L2) -> ONE release fence
//         (wbl2, pushes dirty L2 lines to L3 for cross-XCD readers) -> relaxed add.
// wait:   relaxed polls (plain sc1 load, NO buffer_inv per poll), then ONE
//         acquire fence (inv) after the wake, then barrier.
__device__ __forceinline__ void signal_flag(int* f, int inc) {
    __syncthreads();
    if (threadIdx.x == 0) {
        __builtin_amdgcn_fence(__ATOMIC_RELEASE, "agent");
        __hip_atomic_fetch_add(f, inc, __ATOMIC_RELAXED, __HIP_MEMORY_SCOPE_AGENT);
    }
}
__device__ __forceinline__ void wait_flag(int* f, int target) {
    if (threadIdx.x == 0) {
        while (__hip_atomic_load(f, __ATOMIC_RELAXED, __HIP_MEMORY_SCOPE_AGENT) < target)
            __builtin_amdgcn_s_sleep(8);
        __builtin_amdgcn_fence(__ATOMIC_ACQUIRE, "agent");
    }
    __syncthreads();
}

// ---- weight transpose to bf16 [N][K] with padding ---------------------------
__global__ __launch_bounds__(256) void transpose_bf16(const float* __restrict__ W,
                                                      short* __restrict__ Wt,
                                                      int K, int N, int Kp, int Np) {
    int idx = blockIdx.x * 256 + threadIdx.x;
    if (idx >= Kp * Np) return;
    int n = idx / Kp, kk = idx % Kp;
    float v = (kk < K && n < N) ? W[(size_t)kk * N + n] : 0.f;
    Wt[idx] = f2bf(v);
}

__global__ __launch_bounds__(256) void prep_bias(const float* __restrict__ fb0,
                                                 const float* __restrict__ gb0,
                                                 float* __restrict__ b0c) {
    int i = blockIdx.x * 256 + threadIdx.x;
    if (i < 1024) b0c[i] = (i < kWd) ? fb0[i] : gb0[i - kWd];
}

// ---- init: hist[0]=1, tx pad cols zero, flags zero --------------------------
__global__ __launch_bounds__(256) void init_k(float* __restrict__ hist,
                                              short* __restrict__ txh,
                                              int* __restrict__ flags) {
    int idx = blockIdx.x * 256 + threadIdx.x;
    if (idx < kBH) hist[idx] = 1.0f;
    if (idx < kB * (kKP - kDIN)) {
        int b = idx / (kKP - kDIN), c = idx % (kKP - kDIN);
        txh[(size_t)b * kKP + kDIN + c] = 0;
    }
    if (idx < kNFP) flags[idx] = 0;
}

// ---- 64x64 MFMA GEMM tile (pointers pre-offset to tile origin) --------------
// mode: 0 = relu->bf16, 1 = tanh->bf16, 2 = tanh->fp32
__device__ __forceinline__ void gemm_tile(const short* __restrict__ A, int lda,
                                          const short* __restrict__ B, int K,
                                          const float* __restrict__ bias, int mode,
                                          short* __restrict__ Cb,
                                          float* __restrict__ Cf, int ldc,
                                          short* sA, short* sB, int tid) {
    const int lane = tid & 63;
    const int w = tid >> 6;
    const int wm = (w & 1) * 32;
    const int wn = (w >> 1) * 32;

    const int sr = tid >> 2;
    const int s  = tid & 3;
    const int scol = (s ^ ((sr >> 1) & 3)) * 8;    // inverse-swizzled source col
    const int sdst = sr * 32 + s * 8;              // linear LDS dest

    const short* gA = A + (size_t)sr * lda + scol;
    const short* gB = B + (size_t)sr * K + scol;

    const int nk = K >> 6;                         // 6 or 8 (always even)
    f32x4 acc[2][2] = {};

    gload16(gA,      sA + sdst);
    gload16(gA + 32, sA + 2048 + sdst);
    gload16(gB,      sB + sdst);
    gload16(gB + 32, sB + 2048 + sdst);

    const int fr = lane & 15;
    const int kb = ((lane >> 4) ^ ((fr >> 1) & 3)) * 8;  // swizzled read col
    const int ra0 = (wm + fr) * 32 + kb, ra1 = (wm + 16 + fr) * 32 + kb;
    const int rb0 = (wn + fr) * 32 + kb, rb1 = (wn + 16 + fr) * 32 + kb;

    for (int kt = 0; kt < nk; ++kt) {
        __syncthreads();  // implicit vmcnt(0): buf staged, prev reads done
        const int cur = (kt & 1) * 4096;
        const int nxt = 4096 - cur;
        if (kt + 1 < nk) {
            const int ko = (kt + 1) << 6;
            gload16(gA + ko,      sA + nxt + sdst);
            gload16(gA + ko + 32, sA + nxt + 2048 + sdst);
            gload16(gB + ko,      sB + nxt + sdst);
            gload16(gB + ko + 32, sB + nxt + 2048 + sdst);
        }
#pragma unroll
        for (int ks = 0; ks < 2; ++ks) {
            short8 a0 = *(const short8*)&sA[cur + ks * 2048 + ra0];
            short8 a1 = *(const short8*)&sA[cur + ks * 2048 + ra1];
            short8 b0 = *(const short8*)&sB[cur + ks * 2048 + rb0];
            short8 b1 = *(const short8*)&sB[cur + ks * 2048 + rb1];
            acc[0][0] = __builtin_amdgcn_mfma_f32_16x16x32_bf16(a0, b0, acc[0][0], 0, 0, 0);
            acc[0][1] = __builtin_amdgcn_mfma_f32_16x16x32_bf16(a0, b1, acc[0][1], 0, 0, 0);
            acc[1][0] = __builtin_amdgcn_mfma_f32_16x16x32_bf16(a1, b0, acc[1][0], 0, 0, 0);
            acc[1][1] = __builtin_amdgcn_mfma_f32_16x16x32_bf16(a1, b1, acc[1][1], 0, 0, 0);
        }
    }

    const int rq = (lane >> 4) * 4;
#pragma unroll
    for (int jj = 0; jj < 2; ++jj) {
        int n = wn + jj * 16 + fr;
        float bv = bias[n];
#pragma unroll
        for (int i = 0; i < 2; ++i) {
#pragma unroll
            for (int r = 0; r < 4; ++r) {
                int m = wm + i * 16 + rq + r;
                float v = acc[i][jj][r] + bv;
                if (mode == 0)      Cb[(size_t)m * ldc + n] = f2bf(fmaxf(v, 0.f));
                else if (mode == 1) Cb[(size_t)m * ldc + n] = f2bf(tanhf(v));
                else                Cf[(size_t)m * ldc + n] = tanhf(v);
            }
        }
    }
}

// ---- persistent mega-kernel: all 63 steps, flag-synced per m-tile -----------
// 512 blocks = 32 m-tiles x 16 n-tiles; 2 blocks/CU co-resident (33 KB LDS,
// <=128 VGPR; verified 24% occupancy in round 5) so flag spins cannot deadlock.
__global__ __launch_bounds__(256, 2) void mega(
    float* __restrict__ hist, float* __restrict__ drift,
    short* __restrict__ diffb, short* __restrict__ txh,
    short* __restrict__ b1h, short* __restrict__ b2h,
    const short* __restrict__ W0t, const float* __restrict__ b0c,
    const short* __restrict__ fW1t, const float* __restrict__ fb1,
    const short* __restrict__ gW1t, const float* __restrict__ gb1,
    const short* __restrict__ fW2t, const float* __restrict__ fb2,
    const short* __restrict__ gW2t, const float* __restrict__ gb2,
    const short* __restrict__ fW3t, const float* __restrict__ fb3,
    const short* __restrict__ gW3t, const float* __restrict__ gb3,
    const float* __restrict__ dbt, int* __restrict__ flags) {
    __shared__ __align__(16) short sA[2 * 2 * 2048];
    __shared__ __align__(16) short sB[2 * 2 * 2048];
    __shared__ float ctab[kT * kP];

    const int bid = blockIdx.x;
    const int c = bid & 7, j = bid >> 3;
    const int mt = c + 8 * (j & 3);        // all nt of an mt share an XCD
    const int nt = j >> 2;
    const int m0 = mt * 64;
    const int tid = threadIdx.x;

    for (int k = 0; k < kT; ++k) {
        // ---------- P0: update state + build tx features ----------
        if (k > 0) wait_flag(&flags[(((k - 1) * 5 + 4) * 32 + mt) * kFS], 17);

        {
            const int L = k + 1;
            if (k < kT - 1) {
                float invs = rsqrtf((float)L);
                for (int i = tid; i < L * 4; i += 256) {
                    int jj = i >> 2, pp = i & 3;
                    ctab[i] = cosf(6.283185307179586f * (float)(pp * jj) / (float)L) * invs;
                }
                __syncthreads();
            }
            const int bl = tid >> 6, h = tid & 63;
            const int b = m0 + nt * 4 + bl;
            float xk;
            if (k == 0) {
                xk = 1.0f;
            } else {
                xk = hist[(size_t)(k - 1) * kBH + b * 64 + h] + drift[b * 64 + h];
                const short* dr = diffb + (size_t)b * 1024 + h * kN;
                const float* wr = dbt + (size_t)(k - 1) * kB * kN + b * kN;
#pragma unroll
                for (int n = 0; n < kN; ++n) xk += bf2f(dr[n]) * wr[n];
                hist[(size_t)k * kBH + b * 64 + h] = xk;
            }
            if (k == kT - 1) break;  // final update stored; no more GEMMs

            const float* hp = hist + (size_t)b * 64 + h;
            float a0 = 0.f, a1 = 0.f, a2 = 0.f, a3 = 0.f;
            for (int jj = 0; jj < k; ++jj) {
                float x = hp[(size_t)jj * kBH];
                a0 += x * ctab[jj * 4 + 0];
                a1 += x * ctab[jj * 4 + 1];
                a2 += x * ctab[jj * 4 + 2];
                a3 += x * ctab[jj * 4 + 3];
            }
            a0 += xk * ctab[k * 4 + 0];
            a1 += xk * ctab[k * 4 + 1];
            a2 += xk * ctab[k * 4 + 2];
            a3 += xk * ctab[k * 4 + 3];
            if (L < 2) a1 = 0.f;
            if (L < 4) a2 = 0.f;
            if (L < 6) a3 = 0.f;
            short* th = txh + (size_t)b * kKP;
            th[1 + kH + 0 * kH + h] = f2bf(a0);
            th[1 + kH + 1 * kH + h] = f2bf(a1);
            th[1 + kH + 2 * kH + h] = f2bf(a2);
            th[1 + kH + 3 * kH + h] = f2bf(a3);
            th[1 + h] = f2bf(xk);
            if (h == 0) th[0] = f2bf((float)k);
        }
        signal_flag(&flags[((k * 5 + 0) * 32 + mt) * kFS], 1);

        // ---------- L1: tx[64x384] @ W0t -> b1 (relu) ----------
        wait_flag(&flags[((k * 5 + 0) * 32 + mt) * kFS], 16);
        gemm_tile(txh + (size_t)m0 * kKP, kKP, W0t + (size_t)nt * 64 * kKP, kKP,
                  b0c + nt * 64, 0, b1h + (size_t)m0 * 1024 + nt * 64, nullptr, 1024,
                  sA, sB, tid);
        signal_flag(&flags[((k * 5 + 1) * 32 + mt) * kFS], 1);

        // ---------- L2: b1 -> b2 (relu), f|g halves ----------
        wait_flag(&flags[((k * 5 + 1) * 32 + mt) * kFS], 16);
        if (nt < 8)
            gemm_tile(b1h + (size_t)m0 * 1024, 1024, fW1t + (size_t)nt * 64 * 512, 512,
                      fb1 + nt * 64, 0, b2h + (size_t)m0 * 1024 + nt * 64, nullptr, 1024,
                      sA, sB, tid);
        else
            gemm_tile(b1h + (size_t)m0 * 1024 + 512, 1024, gW1t + (size_t)(nt - 8) * 64 * 512, 512,
                      gb1 + (nt - 8) * 64, 0, b2h + (size_t)m0 * 1024 + nt * 64, nullptr, 1024,
                      sA, sB, tid);
        signal_flag(&flags[((k * 5 + 2) * 32 + mt) * kFS], 1);

        // ---------- L3: b2 -> b1 (relu), f|g halves ----------
        wait_flag(&flags[((k * 5 + 2) * 32 + mt) * kFS], 16);
        if (nt < 8)
            gemm_tile(b2h + (size_t)m0 * 1024, 1024, fW2t + (size_t)nt * 64 * 512, 512,
                      fb2 + nt * 64, 0, b1h + (size_t)m0 * 1024 + nt * 64, nullptr, 1024,
                      sA, sB, tid);
        else
            gemm_tile(b2h + (size_t)m0 * 1024 + 512, 1024, gW2t + (size_t)(nt - 8) * 64 * 512, 512,
                      gb2 + (nt - 8) * 64, 0, b1h + (size_t)m0 * 1024 + nt * 64, nullptr, 1024,
                      sA, sB, tid);
        signal_flag(&flags[((k * 5 + 3) * 32 + mt) * kFS], 1);

        // ---------- L4: drift (tanh,fp32) by nt==0; diffb (tanh,bf16) by all --
        wait_flag(&flags[((k * 5 + 3) * 32 + mt) * kFS], 16);
        if (nt == 0)
            gemm_tile(b1h + (size_t)m0 * 1024, 1024, fW3t, 512,
                      fb3, 2, nullptr, drift + (size_t)m0 * 64, 64, sA, sB, tid);
        gemm_tile(b1h + (size_t)m0 * 1024 + 512, 1024, gW3t + (size_t)nt * 64 * 512, 512,
                  gb3 + nt * 64, 1, diffb + (size_t)m0 * 1024 + nt * 64, nullptr, 1024,
                  sA, sB, tid);
        signal_flag(&flags[((k * 5 + 4) * 32 + mt) * kFS], nt == 0 ? 2 : 1);
    }
}

// ---- readout ----------------------------------------------------------------
__global__ __launch_bounds__(256) void readout_k(const float* __restrict__ hist,
                                                 const float* __restrict__ rW,
                                                 const float* __restrict__ rb,
                                                 const float* __restrict__ ts,
                                                 float* __restrict__ out) {
    __shared__ float sW[kH * kD];
    __shared__ float sb[kD];
    __shared__ float sts[kT];
    int tid = threadIdx.x;
    sW[tid] = rW[tid];
    sW[tid + 256] = rW[tid + 256];
    if (tid < kD) sb[tid] = rb[tid];
    if (tid < kT) sts[tid] = ts[tid];
    __syncthreads();
    int idx = blockIdx.x * 256 + tid;
    int t = idx & (kT - 1), b = idx >> 6;
    const float* xr = hist + (size_t)t * kBH + (size_t)b * kH;
    float acc[kD];
#pragma unroll
    for (int d = 0; d < kD; ++d) acc[d] = sb[d];
    for (int h = 0; h < kH; ++h) {
        float x = xr[h];
#pragma unroll
        for (int d = 0; d < kD; ++d) acc[d] += x * sW[h * kD + d];
    }
    float* o = out + (size_t)((size_t)b * kT + t) * (1 + kD);
    o[0] = sts[t];
#pragma unroll
    for (int d = 0; d < kD; ++d) o[1 + d] = acc[d];
}

extern "C" void kernel_launch(void* const* d_in, const int* in_sizes, int n_in,
                              void* d_out, int out_size, void* d_ws, size_t ws_size,
                              hipStream_t stream) {
    const float* fW0 = (const float*)d_in[0];  const float* fb0 = (const float*)d_in[1];
    const float* fW1 = (const float*)d_in[2];  const float* fb1 = (const float*)d_in[3];
    const float* fW2 = (const float*)d_in[4];  const float* fb2 = (const float*)d_in[5];
    const float* fW3 = (const float*)d_in[6];  const float* fb3 = (const float*)d_in[7];
    const float* gW0 = (const float*)d_in[8];  const float* gb0 = (const float*)d_in[9];
    const float* gW1 = (const float*)d_in[10]; const float* gb1 = (const float*)d_in[11];
    const float* gW2 = (const float*)d_in[12]; const float* gb2 = (const float*)d_in[13];
    const float* gW3 = (const float*)d_in[14]; const float* gb3 = (const float*)d_in[15];
    const float* rW  = (const float*)d_in[16]; const float* rb  = (const float*)d_in[17];
    const float* ts  = (const float*)d_in[18]; const float* dbt = (const float*)d_in[19];
    float* out = (float*)d_out;

    // workspace carve (all 16B aligned). Total ~53 MB.
    char* p = (char*)d_ws;
    float* hist  = (float*)p;  p += (size_t)kT * kBH * 4;     // 33.55 MB
    float* drift = (float*)p;  p += (size_t)kBH * 4;          // 0.52 MB
    float* b0c   = (float*)p;  p += 1024 * 4;
    short* diffb = (short*)p;  p += (size_t)kB * 1024 * 2;    // 4 MB (bf16)
    short* txh   = (short*)p;  p += (size_t)kB * kKP * 2;     // 1.5 MB
    short* b1h   = (short*)p;  p += (size_t)kB * 1024 * 2;    // 4 MB
    short* b2h   = (short*)p;  p += (size_t)kB * 1024 * 2;    // 4 MB
    short* W0t   = (short*)p;  p += (size_t)1024 * kKP * 2;   // 0.75 MB
    short* fW1t  = (short*)p;  p += (size_t)512 * 512 * 2;
    short* gW1t  = (short*)p;  p += (size_t)512 * 512 * 2;
    short* fW2t  = (short*)p;  p += (size_t)512 * 512 * 2;
    short* gW2t  = (short*)p;  p += (size_t)512 * 512 * 2;
    short* fW3t  = (short*)p;  p += (size_t)64 * 512 * 2;
    short* gW3t  = (short*)p;  p += (size_t)1024 * 512 * 2;
    int*   flags = (int*)p;    p += (size_t)kNFP * 4;         // 640 KB (64B/flag)

    auto tgrid = [](int n) { return dim3((n + 255) / 256); };
    transpose_bf16<<<tgrid(kKP * 512), 256, 0, stream>>>(fW0, W0t, kDIN, 512, kKP, 512);
    transpose_bf16<<<tgrid(kKP * 512), 256, 0, stream>>>(gW0, W0t + (size_t)512 * kKP, kDIN, 512, kKP, 512);
    transpose_bf16<<<tgrid(512 * 512), 256, 0, stream>>>(fW1, fW1t, 512, 512, 512, 512);
    transpose_bf16<<<tgrid(512 * 512), 256, 0, stream>>>(gW1, gW1t, 512, 512, 512, 512);
    transpose_bf16<<<tgrid(512 * 512), 256, 0, stream>>>(fW2, fW2t, 512, 512, 512, 512);
    transpose_bf16<<<tgrid(512 * 512), 256, 0, stream>>>(gW2, gW2t, 512, 512, 512, 512);
    transpose_bf16<<<tgrid(512 * 64), 256, 0, stream>>>(fW3, fW3t, 512, 64, 512, 64);
    transpose_bf16<<<tgrid(512 * 1024), 256, 0, stream>>>(gW3, gW3t, 512, 1024, 512, 1024);
    prep_bias<<<dim3(4), 256, 0, stream>>>(fb0, gb0, b0c);
    init_k<<<dim3((kNFP + 255) / 256), 256, 0, stream>>>(hist, txh, flags);

    mega<<<dim3(512), 256, 0, stream>>>(hist, drift, diffb, txh, b1h, b2h,
                                        W0t, b0c, fW1t, fb1, gW1t, gb1,
                                        fW2t, fb2, gW2t, gb2, fW3t, fb3, gW3t, gb3,
                                        dbt, flags);

    readout_k<<<dim3(kB * kT / 256), 256, 0, stream>>>(hist, rW, rb, ts, out);
}

// Round 8
// 3922.686 us; speedup vs baseline: 9.6772x; 2.1886x over previous
//
#include <hip/hip_runtime.h>
#include <math.h>

// Problem constants
constexpr int kH   = 64;
constexpr int kP   = 4;
constexpr int kN   = 16;
constexpr int kD   = 8;
constexpr int kT   = 64;
constexpr int kWd  = 512;
constexpr int kB   = 2048;
constexpr int kDIN = 1 + kH + kP * kH;  // 321
constexpr int kKP  = 384;               // K padded to multiple of 64
constexpr int kBH  = kB * kH;           // 131072
constexpr int kNF  = 64 * 5 * 32;       // logical flag count
constexpr int kFS  = 16;                // flag stride (ints) = 64B padding
constexpr int kNFP = kNF * kFS;         // padded flag ints

typedef __attribute__((ext_vector_type(8))) short short8;
typedef __attribute__((ext_vector_type(4))) float f32x4;

// ---- bf16 helpers -----------------------------------------------------------
__device__ __forceinline__ short f2bf(float x) {
    union { float f; unsigned u; } v; v.f = x;
    unsigned r = (v.u + 0x7FFFu + ((v.u >> 16) & 1u)) >> 16;
    return (short)r;
}
__device__ __forceinline__ float bf2f(short h) {
    union { unsigned u; float f; } v; v.u = ((unsigned)(unsigned short)h) << 16;
    return v.f;
}

// ---- async global->LDS 16B --------------------------------------------------
// plain: L1-cacheable (read-only weights).
__device__ __forceinline__ void gload16(const short* g, short* l) {
    __builtin_amdgcn_global_load_lds(
        (const __attribute__((address_space(1))) unsigned int*)g,
        (__attribute__((address_space(3))) unsigned int*)l, 16, 0, 0);
}
// sc0 (aux=1): L1-bypass -> reads the (same-XCD) L2 directly. Used for
// cross-block-produced activations so no L1 invalidate is ever needed.
__device__ __forceinline__ void gload16_c(const short* g, short* l) {
    __builtin_amdgcn_global_load_lds(
        (const __attribute__((address_space(1))) unsigned int*)g,
        (__attribute__((address_space(3))) unsigned int*)l, 16, 0, 1);
}

// ---- inter-block flag sync (same-XCD producers/consumers; NO TCC cache ops) --
// release: vmcnt(0) per thread (stores complete at L2 = intra-XCD coherence
// point) -> barrier -> ONE relaxed atomicAdd. No buffer_wbl2.
// wait: relaxed polls (no buffer_inv per poll or per wake) -> barrier.
// Consumers handle L1 staleness via sc0 loads instead of invalidates.
__device__ __forceinline__ void signal_flag(int* f, int inc) {
    asm volatile("s_waitcnt vmcnt(0)" ::: "memory");
    __syncthreads();
    if (threadIdx.x == 0)
        __hip_atomic_fetch_add(f, inc, __ATOMIC_RELAXED, __HIP_MEMORY_SCOPE_AGENT);
}
__device__ __forceinline__ void wait_flag(int* f, int target) {
    if (threadIdx.x == 0) {
        while (__hip_atomic_load(f, __ATOMIC_RELAXED, __HIP_MEMORY_SCOPE_AGENT) < target)
            __builtin_amdgcn_s_sleep(8);
    }
    __syncthreads();
}

// ---- weight transpose to bf16 [N][K] with padding ---------------------------
__global__ __launch_bounds__(256) void transpose_bf16(const float* __restrict__ W,
                                                      short* __restrict__ Wt,
                                                      int K, int N, int Kp, int Np) {
    int idx = blockIdx.x * 256 + threadIdx.x;
    if (idx >= Kp * Np) return;
    int n = idx / Kp, kk = idx % Kp;
    float v = (kk < K && n < N) ? W[(size_t)kk * N + n] : 0.f;
    Wt[idx] = f2bf(v);
}

__global__ __launch_bounds__(256) void prep_bias(const float* __restrict__ fb0,
                                                 const float* __restrict__ gb0,
                                                 float* __restrict__ b0c) {
    int i = blockIdx.x * 256 + threadIdx.x;
    if (i < 1024) b0c[i] = (i < kWd) ? fb0[i] : gb0[i - kWd];
}

// ---- init: hist[0]=1, tx pad cols zero, flags zero --------------------------
__global__ __launch_bounds__(256) void init_k(float* __restrict__ hist,
                                              short* __restrict__ txh,
                                              int* __restrict__ flags) {
    int idx = blockIdx.x * 256 + threadIdx.x;
    if (idx < kBH) hist[idx] = 1.0f;
    if (idx < kB * (kKP - kDIN)) {
        int b = idx / (kKP - kDIN), c = idx % (kKP - kDIN);
        txh[(size_t)b * kKP + kDIN + c] = 0;
    }
    if (idx < kNFP) flags[idx] = 0;
}

// ---- 64x64 MFMA GEMM tile (pointers pre-offset to tile origin) --------------
// mode: 0 = relu->bf16, 1 = tanh->bf16, 2 = tanh->fp32
// A staged with sc0 (cross-block data), B staged plain (weights, L1-cached).
__device__ __forceinline__ void gemm_tile(const short* __restrict__ A, int lda,
                                          const short* __restrict__ B, int K,
                                          const float* __restrict__ bias, int mode,
                                          short* __restrict__ Cb,
                                          float* __restrict__ Cf, int ldc,
                                          short* sA, short* sB, int tid) {
    const int lane = tid & 63;
    const int w = tid >> 6;
    const int wm = (w & 1) * 32;
    const int wn = (w >> 1) * 32;

    const int sr = tid >> 2;
    const int s  = tid & 3;
    const int scol = (s ^ ((sr >> 1) & 3)) * 8;    // inverse-swizzled source col
    const int sdst = sr * 32 + s * 8;              // linear LDS dest

    const short* gA = A + (size_t)sr * lda + scol;
    const short* gB = B + (size_t)sr * K + scol;

    const int nk = K >> 6;                         // 6 or 8 (always even)
    f32x4 acc[2][2] = {};

    gload16_c(gA,      sA + sdst);
    gload16_c(gA + 32, sA + 2048 + sdst);
    gload16(gB,      sB + sdst);
    gload16(gB + 32, sB + 2048 + sdst);

    const int fr = lane & 15;
    const int kb = ((lane >> 4) ^ ((fr >> 1) & 3)) * 8;  // swizzled read col
    const int ra0 = (wm + fr) * 32 + kb, ra1 = (wm + 16 + fr) * 32 + kb;
    const int rb0 = (wn + fr) * 32 + kb, rb1 = (wn + 16 + fr) * 32 + kb;

    for (int kt = 0; kt < nk; ++kt) {
        __syncthreads();  // implicit vmcnt(0): buf staged, prev reads done
        const int cur = (kt & 1) * 4096;
        const int nxt = 4096 - cur;
        if (kt + 1 < nk) {
            const int ko = (kt + 1) << 6;
            gload16_c(gA + ko,      sA + nxt + sdst);
            gload16_c(gA + ko + 32, sA + nxt + 2048 + sdst);
            gload16(gB + ko,      sB + nxt + sdst);
            gload16(gB + ko + 32, sB + nxt + 2048 + sdst);
        }
#pragma unroll
        for (int ks = 0; ks < 2; ++ks) {
            short8 a0 = *(const short8*)&sA[cur + ks * 2048 + ra0];
            short8 a1 = *(const short8*)&sA[cur + ks * 2048 + ra1];
            short8 b0 = *(const short8*)&sB[cur + ks * 2048 + rb0];
            short8 b1 = *(const short8*)&sB[cur + ks * 2048 + rb1];
            acc[0][0] = __builtin_amdgcn_mfma_f32_16x16x32_bf16(a0, b0, acc[0][0], 0, 0, 0);
            acc[0][1] = __builtin_amdgcn_mfma_f32_16x16x32_bf16(a0, b1, acc[0][1], 0, 0, 0);
            acc[1][0] = __builtin_amdgcn_mfma_f32_16x16x32_bf16(a1, b0, acc[1][0], 0, 0, 0);
            acc[1][1] = __builtin_amdgcn_mfma_f32_16x16x32_bf16(a1, b1, acc[1][1], 0, 0, 0);
        }
    }

    const int rq = (lane >> 4) * 4;
#pragma unroll
    for (int jj = 0; jj < 2; ++jj) {
        int n = wn + jj * 16 + fr;
        float bv = bias[n];
#pragma unroll
        for (int i = 0; i < 2; ++i) {
#pragma unroll
            for (int r = 0; r < 4; ++r) {
                int m = wm + i * 16 + rq + r;
                float v = acc[i][jj][r] + bv;
                if (mode == 0)      Cb[(size_t)m * ldc + n] = f2bf(fmaxf(v, 0.f));
                else if (mode == 1) Cb[(size_t)m * ldc + n] = f2bf(tanhf(v));
                else                Cf[(size_t)m * ldc + n] = tanhf(v);
            }
        }
    }
}

// ---- persistent mega-kernel: all 63 steps, flag-synced per m-tile -----------
// 512 blocks = 32 m-tiles x 16 n-tiles; 2 blocks/CU co-resident. All cross-
// block deps are within an m-tile, whose 16 blocks share an XCD (round-robin
// dispatch), so the shared L2 is the coherence point: no agent fences needed.
__global__ __launch_bounds__(256, 2) void mega(
    float* __restrict__ hist, float* __restrict__ drift,
    short* __restrict__ diffb, short* __restrict__ txh,
    short* __restrict__ b1h, short* __restrict__ b2h,
    const short* __restrict__ W0t, const float* __restrict__ b0c,
    const short* __restrict__ fW1t, const float* __restrict__ fb1,
    const short* __restrict__ gW1t, const float* __restrict__ gb1,
    const short* __restrict__ fW2t, const float* __restrict__ fb2,
    const short* __restrict__ gW2t, const float* __restrict__ gb2,
    const short* __restrict__ fW3t, const float* __restrict__ fb3,
    const short* __restrict__ gW3t, const float* __restrict__ gb3,
    const float* __restrict__ dbt, int* __restrict__ flags) {
    __shared__ __align__(16) short sA[2 * 2 * 2048];
    __shared__ __align__(16) short sB[2 * 2 * 2048];
    __shared__ float ctab[kT * kP];

    const int bid = blockIdx.x;
    const int c = bid & 7, j = bid >> 3;
    const int mt = c + 8 * (j & 3);        // all nt of an mt share an XCD
    const int nt = j >> 2;
    const int m0 = mt * 64;
    const int tid = threadIdx.x;

    for (int k = 0; k < kT; ++k) {
        // ---------- P0: update state + build tx features ----------
        if (k > 0) wait_flag(&flags[(((k - 1) * 5 + 4) * 32 + mt) * kFS], 17);

        {
            const int L = k + 1;
            if (k < kT - 1) {
                float invs = rsqrtf((float)L);
                for (int i = tid; i < L * 4; i += 256) {
                    int jj = i >> 2, pp = i & 3;
                    ctab[i] = cosf(6.283185307179586f * (float)(pp * jj) / (float)L) * invs;
                }
                __syncthreads();
            }
            const int bl = tid >> 6, h = tid & 63;
            const int b = m0 + nt * 4 + bl;
            float xk;
            if (k == 0) {
                xk = 1.0f;
            } else {
                // drift/diffb were written by other blocks (same XCD): read via
                // relaxed atomic loads (L1-bypass, independent -> they pipeline).
                float dv = __hip_atomic_load(drift + b * 64 + h, __ATOMIC_RELAXED,
                                             __HIP_MEMORY_SCOPE_AGENT);
                xk = hist[(size_t)(k - 1) * kBH + b * 64 + h] + dv;
                const int* dr = (const int*)(diffb + (size_t)b * 1024 + h * kN);
                const float* wr = dbt + (size_t)(k - 1) * kB * kN + b * kN;
#pragma unroll
                for (int n = 0; n < 8; ++n) {
                    int pk = __hip_atomic_load(dr + n, __ATOMIC_RELAXED,
                                               __HIP_MEMORY_SCOPE_AGENT);
                    xk += bf2f((short)(pk & 0xffff)) * wr[2 * n];
                    xk += bf2f((short)(pk >> 16))    * wr[2 * n + 1];
                }
                hist[(size_t)k * kBH + b * 64 + h] = xk;
            }
            if (k == kT - 1) break;  // final update stored; no more GEMMs

            const float* hp = hist + (size_t)b * 64 + h;
            float a0 = 0.f, a1 = 0.f, a2 = 0.f, a3 = 0.f;
            for (int jj = 0; jj < k; ++jj) {
                float x = hp[(size_t)jj * kBH];
                a0 += x * ctab[jj * 4 + 0];
                a1 += x * ctab[jj * 4 + 1];
                a2 += x * ctab[jj * 4 + 2];
                a3 += x * ctab[jj * 4 + 3];
            }
            a0 += xk * ctab[k * 4 + 0];
            a1 += xk * ctab[k * 4 + 1];
            a2 += xk * ctab[k * 4 + 2];
            a3 += xk * ctab[k * 4 + 3];
            if (L < 2) a1 = 0.f;
            if (L < 4) a2 = 0.f;
            if (L < 6) a3 = 0.f;
            short* th = txh + (size_t)b * kKP;
            th[1 + kH + 0 * kH + h] = f2bf(a0);
            th[1 + kH + 1 * kH + h] = f2bf(a1);
            th[1 + kH + 2 * kH + h] = f2bf(a2);
            th[1 + kH + 3 * kH + h] = f2bf(a3);
            th[1 + h] = f2bf(xk);
            if (h == 0) th[0] = f2bf((float)k);
        }
        signal_flag(&flags[((k * 5 + 0) * 32 + mt) * kFS], 1);

        // ---------- L1: tx[64x384] @ W0t -> b1 (relu) ----------
        wait_flag(&flags[((k * 5 + 0) * 32 + mt) * kFS], 16);
        gemm_tile(txh + (size_t)m0 * kKP, kKP, W0t + (size_t)nt * 64 * kKP, kKP,
                  b0c + nt * 64, 0, b1h + (size_t)m0 * 1024 + nt * 64, nullptr, 1024,
                  sA, sB, tid);
        signal_flag(&flags[((k * 5 + 1) * 32 + mt) * kFS], 1);

        // ---------- L2: b1 -> b2 (relu), f|g halves ----------
        wait_flag(&flags[((k * 5 + 1) * 32 + mt) * kFS], 16);
        if (nt < 8)
            gemm_tile(b1h + (size_t)m0 * 1024, 1024, fW1t + (size_t)nt * 64 * 512, 512,
                      fb1 + nt * 64, 0, b2h + (size_t)m0 * 1024 + nt * 64, nullptr, 1024,
                      sA, sB, tid);
        else
            gemm_tile(b1h + (size_t)m0 * 1024 + 512, 1024, gW1t + (size_t)(nt - 8) * 64 * 512, 512,
                      gb1 + (nt - 8) * 64, 0, b2h + (size_t)m0 * 1024 + nt * 64, nullptr, 1024,
                      sA, sB, tid);
        signal_flag(&flags[((k * 5 + 2) * 32 + mt) * kFS], 1);

        // ---------- L3: b2 -> b1 (relu), f|g halves ----------
        wait_flag(&flags[((k * 5 + 2) * 32 + mt) * kFS], 16);
        if (nt < 8)
            gemm_tile(b2h + (size_t)m0 * 1024, 1024, fW2t + (size_t)nt * 64 * 512, 512,
                      fb2 + nt * 64, 0, b1h + (size_t)m0 * 1024 + nt * 64, nullptr, 1024,
                      sA, sB, tid);
        else
            gemm_tile(b2h + (size_t)m0 * 1024 + 512, 1024, gW2t + (size_t)(nt - 8) * 64 * 512, 512,
                      gb2 + (nt - 8) * 64, 0, b1h + (size_t)m0 * 1024 + nt * 64, nullptr, 1024,
                      sA, sB, tid);
        signal_flag(&flags[((k * 5 + 3) * 32 + mt) * kFS], 1);

        // ---------- L4: drift (tanh,fp32) by nt==0; diffb (tanh,bf16) by all --
        wait_flag(&flags[((k * 5 + 3) * 32 + mt) * kFS], 16);
        if (nt == 0)
            gemm_tile(b1h + (size_t)m0 * 1024, 1024, fW3t, 512,
                      fb3, 2, nullptr, drift + (size_t)m0 * 64, 64, sA, sB, tid);
        gemm_tile(b1h + (size_t)m0 * 1024 + 512, 1024, gW3t + (size_t)nt * 64 * 512, 512,
                  gb3 + nt * 64, 1, diffb + (size_t)m0 * 1024 + nt * 64, nullptr, 1024,
                  sA, sB, tid);
        signal_flag(&flags[((k * 5 + 4) * 32 + mt) * kFS], nt == 0 ? 2 : 1);
    }
}

// ---- readout ----------------------------------------------------------------
__global__ __launch_bounds__(256) void readout_k(const float* __restrict__ hist,
                                                 const float* __restrict__ rW,
                                                 const float* __restrict__ rb,
                                                 const float* __restrict__ ts,
                                                 float* __restrict__ out) {
    __shared__ float sW[kH * kD];
    __shared__ float sb[kD];
    __shared__ float sts[kT];
    int tid = threadIdx.x;
    sW[tid] = rW[tid];
    sW[tid + 256] = rW[tid + 256];
    if (tid < kD) sb[tid] = rb[tid];
    if (tid < kT) sts[tid] = ts[tid];
    __syncthreads();
    int idx = blockIdx.x * 256 + tid;
    int t = idx & (kT - 1), b = idx >> 6;
    const float* xr = hist + (size_t)t * kBH + (size_t)b * kH;
    float acc[kD];
#pragma unroll
    for (int d = 0; d < kD; ++d) acc[d] = sb[d];
    for (int h = 0; h < kH; ++h) {
        float x = xr[h];
#pragma unroll
        for (int d = 0; d < kD; ++d) acc[d] += x * sW[h * kD + d];
    }
    float* o = out + (size_t)((size_t)b * kT + t) * (1 + kD);
    o[0] = sts[t];
#pragma unroll
    for (int d = 0; d < kD; ++d) o[1 + d] = acc[d];
}

extern "C" void kernel_launch(void* const* d_in, const int* in_sizes, int n_in,
                              void* d_out, int out_size, void* d_ws, size_t ws_size,
                              hipStream_t stream) {
    const float* fW0 = (const float*)d_in[0];  const float* fb0 = (const float*)d_in[1];
    const float* fW1 = (const float*)d_in[2];  const float* fb1 = (const float*)d_in[3];
    const float* fW2 = (const float*)d_in[4];  const float* fb2 = (const float*)d_in[5];
    const float* fW3 = (const float*)d_in[6];  const float* fb3 = (const float*)d_in[7];
    const float* gW0 = (const float*)d_in[8];  const float* gb0 = (const float*)d_in[9];
    const float* gW1 = (const float*)d_in[10]; const float* gb1 = (const float*)d_in[11];
    const float* gW2 = (const float*)d_in[12]; const float* gb2 = (const float*)d_in[13];
    const float* gW3 = (const float*)d_in[14]; const float* gb3 = (const float*)d_in[15];
    const float* rW  = (const float*)d_in[16]; const float* rb  = (const float*)d_in[17];
    const float* ts  = (const float*)d_in[18]; const float* dbt = (const float*)d_in[19];
    float* out = (float*)d_out;

    // workspace carve (all 16B aligned). Total ~53 MB.
    char* p = (char*)d_ws;
    float* hist  = (float*)p;  p += (size_t)kT * kBH * 4;     // 33.55 MB
    float* drift = (float*)p;  p += (size_t)kBH * 4;          // 0.52 MB
    float* b0c   = (float*)p;  p += 1024 * 4;
    short* diffb = (short*)p;  p += (size_t)kB * 1024 * 2;    // 4 MB (bf16)
    short* txh   = (short*)p;  p += (size_t)kB * kKP * 2;     // 1.5 MB
    short* b1h   = (short*)p;  p += (size_t)kB * 1024 * 2;    // 4 MB
    short* b2h   = (short*)p;  p += (size_t)kB * 1024 * 2;    // 4 MB
    short* W0t   = (short*)p;  p += (size_t)1024 * kKP * 2;   // 0.75 MB
    short* fW1t  = (short*)p;  p += (size_t)512 * 512 * 2;
    short* gW1t  = (short*)p;  p += (size_t)512 * 512 * 2;
    short* fW2t  = (short*)p;  p += (size_t)512 * 512 * 2;
    short* gW2t  = (short*)p;  p += (size_t)512 * 512 * 2;
    short* fW3t  = (short*)p;  p += (size_t)64 * 512 * 2;
    short* gW3t  = (short*)p;  p += (size_t)1024 * 512 * 2;
    int*   flags = (int*)p;    p += (size_t)kNFP * 4;         // 640 KB (64B/flag)

    auto tgrid = [](int n) { return dim3((n + 255) / 256); };
    transpose_bf16<<<tgrid(kKP * 512), 256, 0, stream>>>(fW0, W0t, kDIN, 512, kKP, 512);
    transpose_bf16<<<tgrid(kKP * 512), 256, 0, stream>>>(gW0, W0t + (size_t)512 * kKP, kDIN, 512, kKP, 512);
    transpose_bf16<<<tgrid(512 * 512), 256, 0, stream>>>(fW1, fW1t, 512, 512, 512, 512);
    transpose_bf16<<<tgrid(512 * 512), 256, 0, stream>>>(gW1, gW1t, 512, 512, 512, 512);
    transpose_bf16<<<tgrid(512 * 512), 256, 0, stream>>>(fW2, fW2t, 512, 512, 512, 512);
    transpose_bf16<<<tgrid(512 * 512), 256, 0, stream>>>(gW2, gW2t, 512, 512, 512, 512);
    transpose_bf16<<<tgrid(512 * 64), 256, 0, stream>>>(fW3, fW3t, 512, 64, 512, 64);
    transpose_bf16<<<tgrid(512 * 1024), 256, 0, stream>>>(gW3, gW3t, 512, 1024, 512, 1024);
    prep_bias<<<dim3(4), 256, 0, stream>>>(fb0, gb0, b0c);
    init_k<<<dim3((kNFP + 255) / 256), 256, 0, stream>>>(hist, txh, flags);

    mega<<<dim3(512), 256, 0, stream>>>(hist, drift, diffb, txh, b1h, b2h,
                                        W0t, b0c, fW1t, fb1, gW1t, gb1,
                                        fW2t, fb2, gW2t, gb2, fW3t, fb3, gW3t, gb3,
                                        dbt, flags);

    readout_k<<<dim3(kB * kT / 256), 256, 0, stream>>>(hist, rW, rb, ts, out);
}

// Round 9
// 2608.430 us; speedup vs baseline: 14.5530x; 1.5038x over previous
//
#include <hip/hip_runtime.h>
#include <math.h>

// Problem constants
constexpr int kH   = 64;
constexpr int kP   = 4;
constexpr int kN   = 16;
constexpr int kD   = 8;
constexpr int kT   = 64;
constexpr int kWd  = 512;
constexpr int kB   = 2048;
constexpr int kDIN = 1 + kH + kP * kH;  // 321
constexpr int kKP  = 384;               // K padded to multiple of 64
constexpr int kBH  = kB * kH;           // 131072

typedef __attribute__((ext_vector_type(8))) short short8;
typedef __attribute__((ext_vector_type(4))) float f32x4;
typedef __attribute__((ext_vector_type(4))) float float4v;

// ---- bf16 helpers -----------------------------------------------------------
__device__ __forceinline__ short f2bf(float x) {
    union { float f; unsigned u; } v; v.f = x;
    unsigned r = (v.u + 0x7FFFu + ((v.u >> 16) & 1u)) >> 16;
    return (short)r;
}

// ---- async global->LDS 16B --------------------------------------------------
__device__ __forceinline__ void gload16(const short* g, short* l) {
    __builtin_amdgcn_global_load_lds(
        (const __attribute__((address_space(1))) unsigned int*)g,
        (__attribute__((address_space(3))) unsigned int*)l, 16, 0, 0);
}

// ---- weight transpose to bf16 [N][K] with padding ---------------------------
__global__ __launch_bounds__(256) void transpose_bf16(const float* __restrict__ W,
                                                      short* __restrict__ Wt,
                                                      int K, int N, int Kp, int Np) {
    int idx = blockIdx.x * 256 + threadIdx.x;
    if (idx >= Kp * Np) return;
    int n = idx / Kp, kk = idx % Kp;
    float v = (kk < K && n < N) ? W[(size_t)kk * N + n] : 0.f;
    Wt[idx] = f2bf(v);
}

__global__ __launch_bounds__(256) void prep_bias(const float* __restrict__ fb0,
                                                 const float* __restrict__ gb0,
                                                 float* __restrict__ b0c) {
    int i = blockIdx.x * 256 + threadIdx.x;
    if (i < 1024) b0c[i] = (i < kWd) ? fb0[i] : gb0[i - kWd];
}

// ---- init: hist[0]=1, tx pad cols zero --------------------------------------
__global__ __launch_bounds__(256) void init_k(float* __restrict__ hist,
                                              short* __restrict__ txh) {
    int idx = blockIdx.x * 256 + threadIdx.x;
    if (idx < kBH) hist[idx] = 1.0f;
    if (idx < kB * (kKP - kDIN)) {
        int b = idx / (kKP - kDIN), c = idx % (kKP - kDIN);
        txh[(size_t)b * kKP + kDIN + c] = 0;
    }
}

// ---- fused: state update (step k) + build tx features -----------------------
__global__ __launch_bounds__(256) void step_pre(float* __restrict__ hist,
                                                const float* __restrict__ drift,
                                                const float* __restrict__ xdelta,
                                                short* __restrict__ txh, int k) {
    const int L = k + 1;
    __shared__ float ctab[kT * kP];
    int tid = threadIdx.x;
    float invs = rsqrtf((float)L);
    for (int i = tid; i < L * kP; i += 256) {
        int j = i >> 2, p = i & 3;
        ctab[i] = cosf(6.283185307179586f * (float)(p * j) / (float)L) * invs;
    }
    __syncthreads();
    int idx = blockIdx.x * 256 + tid;
    int b = idx >> 6, h = idx & 63;
    float xk;
    if (k == 0) {
        xk = 1.0f;
    } else {
        xk = hist[(size_t)(k - 1) * kBH + idx] + drift[idx] + xdelta[idx];
        hist[(size_t)k * kBH + idx] = xk;
    }
    const float* hp = hist + (size_t)b * kH + h;
    float a0 = 0.f, a1 = 0.f, a2 = 0.f, a3 = 0.f;
    for (int j = 0; j < k; ++j) {
        float x = hp[(size_t)j * kBH];
        a0 += x * ctab[j * 4 + 0];
        a1 += x * ctab[j * 4 + 1];
        a2 += x * ctab[j * 4 + 2];
        a3 += x * ctab[j * 4 + 3];
    }
    a0 += xk * ctab[k * 4 + 0];
    a1 += xk * ctab[k * 4 + 1];
    a2 += xk * ctab[k * 4 + 2];
    a3 += xk * ctab[k * 4 + 3];
    if (L < 2) a1 = 0.f;
    if (L < 4) a2 = 0.f;
    if (L < 6) a3 = 0.f;
    short* th = txh + (size_t)b * kKP;
    th[1 + kH + 0 * kH + h] = f2bf(a0);
    th[1 + kH + 1 * kH + h] = f2bf(a1);
    th[1 + kH + 2 * kH + h] = f2bf(a2);
    th[1 + kH + 3 * kH + h] = f2bf(a3);
    th[1 + h] = f2bf(xk);
    if (h == 0) th[0] = f2bf((float)k);
}

// ---- MFMA GEMM, BM=128: C = act(A @ Wt^T + bias) ----------------------------
// 512 threads = 8 waves (4M x 2N), block tile 128x64, wave tile 32x32 (same
// verified fragment math as the 2548us kernel). BK=64 as two 32-col panels,
// double-buffered, ONE __syncthreads per K-tile (implicit vmcnt(0) drains the
// prefetch issued last iteration). XOR swizzle (slot^=(row>>1)&3) on global
// source + LDS read -> 2-way bank conflicts (free).
struct MArg {
    const short* A;                     // [2048 x lda] bf16
    const short* Bt;                    // [Np x K] bf16 (transposed weights)
    const float* bias;
    short* Cb;                          // bf16 out (act=0 relu)
    int K, lda, ldc, Nw;
};

__global__ __launch_bounds__(512, 1) void gemm128(MArg f, MArg g, int ysplit) {
    const int y = blockIdx.y;
    MArg a;
    int n0;
    if (y < ysplit) { a = f; n0 = y * 64; }
    else            { a = g; n0 = (y - ysplit) * 64; }
    const int m0 = blockIdx.x * 128;

    __shared__ __align__(16) short sA[2][2][128 * 32];   // 32 KB
    __shared__ __align__(16) short sB[2][2][64 * 32];    // 16 KB

    const int tid = threadIdx.x;
    const int lane = tid & 63;
    const int w = tid >> 6;                 // 8 waves
    const int wm = (w & 3) * 32;            // 4 M slots
    const int wn = (w >> 2) * 32;           // 2 N slots

    const int sr = tid >> 2;                       // A staging row 0..127
    const int s  = tid & 3;
    const int scol = (s ^ ((sr >> 1) & 3)) * 8;
    const int sdst = sr * 32 + s * 8;
    const bool doB = tid < 256;                    // B rows 0..63

    const short* gA = a.A  + (size_t)(m0 + sr) * a.lda + scol;
    const short* gB = a.Bt + (size_t)(n0 + sr) * a.K   + scol;  // valid when doB

    const int nk = a.K >> 6;
    f32x4 acc[2][2] = {};

    gload16(gA,      &sA[0][0][sdst]);
    gload16(gA + 32, &sA[0][1][sdst]);
    if (doB) {
        gload16(gB,      &sB[0][0][sdst]);
        gload16(gB + 32, &sB[0][1][sdst]);
    }

    const int fr = lane & 15;
    const int kb = ((lane >> 4) ^ ((fr >> 1) & 3)) * 8;
    const int ra0 = (wm + fr) * 32 + kb, ra1 = (wm + 16 + fr) * 32 + kb;
    const int rb0 = (wn + fr) * 32 + kb, rb1 = (wn + 16 + fr) * 32 + kb;

    for (int kt = 0; kt < nk; ++kt) {
        __syncthreads();
        const int cur = kt & 1, nxt = cur ^ 1;
        if (kt + 1 < nk) {
            const int ko = (kt + 1) << 6;
            gload16(gA + ko,      &sA[nxt][0][sdst]);
            gload16(gA + ko + 32, &sA[nxt][1][sdst]);
            if (doB) {
                gload16(gB + ko,      &sB[nxt][0][sdst]);
                gload16(gB + ko + 32, &sB[nxt][1][sdst]);
            }
        }
#pragma unroll
        for (int ks = 0; ks < 2; ++ks) {
            short8 a0 = *(const short8*)&sA[cur][ks][ra0];
            short8 a1 = *(const short8*)&sA[cur][ks][ra1];
            short8 b0 = *(const short8*)&sB[cur][ks][rb0];
            short8 b1 = *(const short8*)&sB[cur][ks][rb1];
            acc[0][0] = __builtin_amdgcn_mfma_f32_16x16x32_bf16(a0, b0, acc[0][0], 0, 0, 0);
            acc[0][1] = __builtin_amdgcn_mfma_f32_16x16x32_bf16(a0, b1, acc[0][1], 0, 0, 0);
            acc[1][0] = __builtin_amdgcn_mfma_f32_16x16x32_bf16(a1, b0, acc[1][0], 0, 0, 0);
            acc[1][1] = __builtin_amdgcn_mfma_f32_16x16x32_bf16(a1, b1, acc[1][1], 0, 0, 0);
        }
    }

    const int rq = (lane >> 4) * 4;
#pragma unroll
    for (int jj = 0; jj < 2; ++jj) {
        int n = n0 + wn + jj * 16 + fr;
        if (n >= a.Nw) continue;
        float bv = a.bias[n];
#pragma unroll
        for (int i = 0; i < 2; ++i)
#pragma unroll
            for (int r = 0; r < 4; ++r) {
                int m = m0 + wm + i * 16 + rq + r;
                a.Cb[(size_t)m * a.ldc + n] = f2bf(fmaxf(acc[i][jj][r] + bv, 0.f));
            }
    }
}

// ---- L4: drift GEMM (y==0) and g GEMM with fused noise contraction (y>=1) ---
// g blocks never materialize diff: tanh tile reduced against dbt[k] in-register
// (16-lane fr group == the 16 noise dims of one h) -> xdelta[b][h] fp32.
__global__ __launch_bounds__(512, 1) void l4_kernel(const short* __restrict__ b1,
                                                    const short* __restrict__ fW3t,
                                                    const float* __restrict__ fb3,
                                                    const short* __restrict__ gW3t,
                                                    const float* __restrict__ gb3,
                                                    const float* __restrict__ dbt,
                                                    float* __restrict__ drift,
                                                    float* __restrict__ xdelta, int k) {
    const int y = blockIdx.y;
    const bool isF = (y == 0);
    const int nt = isF ? 0 : y - 1;
    const int n0 = nt * 64;
    const int m0 = blockIdx.x * 128;

    __shared__ __align__(16) short sA[2][2][128 * 32];   // 32 KB
    __shared__ __align__(16) short sB[2][2][64 * 32];    // 16 KB
    __shared__ float sdb[128 * 16];                      // 8 KB (dbt tile)

    const int tid = threadIdx.x;
    const int lane = tid & 63;
    const int w = tid >> 6;
    const int wm = (w & 3) * 32;
    const int wn = (w >> 2) * 32;

    const short* A = b1 + (isF ? 0 : 512);
    const short* Bt = isF ? fW3t : gW3t + (size_t)n0 * 512;
    const float* bias = isF ? fb3 : gb3 + n0;
    const int K = 512;

    if (!isF)
        *(float4v*)&sdb[tid * 4] =
            ((const float4v*)(dbt + ((size_t)k * kB + m0) * kN))[tid];

    const int sr = tid >> 2;
    const int s  = tid & 3;
    const int scol = (s ^ ((sr >> 1) & 3)) * 8;
    const int sdst = sr * 32 + s * 8;
    const bool doB = tid < 256;

    const short* gA = A + (size_t)(m0 + sr) * 1024 + scol;
    const short* gB = Bt + (size_t)sr * K + scol;

    f32x4 acc[2][2] = {};
    gload16(gA,      &sA[0][0][sdst]);
    gload16(gA + 32, &sA[0][1][sdst]);
    if (doB) {
        gload16(gB,      &sB[0][0][sdst]);
        gload16(gB + 32, &sB[0][1][sdst]);
    }

    const int fr = lane & 15;
    const int kb = ((lane >> 4) ^ ((fr >> 1) & 3)) * 8;
    const int ra0 = (wm + fr) * 32 + kb, ra1 = (wm + 16 + fr) * 32 + kb;
    const int rb0 = (wn + fr) * 32 + kb, rb1 = (wn + 16 + fr) * 32 + kb;

    for (int kt = 0; kt < 8; ++kt) {
        __syncthreads();
        const int cur = kt & 1, nxt = cur ^ 1;
        if (kt + 1 < 8) {
            const int ko = (kt + 1) << 6;
            gload16(gA + ko,      &sA[nxt][0][sdst]);
            gload16(gA + ko + 32, &sA[nxt][1][sdst]);
            if (doB) {
                gload16(gB + ko,      &sB[nxt][0][sdst]);
                gload16(gB + ko + 32, &sB[nxt][1][sdst]);
            }
        }
#pragma unroll
        for (int ks = 0; ks < 2; ++ks) {
            short8 a0 = *(const short8*)&sA[cur][ks][ra0];
            short8 a1 = *(const short8*)&sA[cur][ks][ra1];
            short8 b0 = *(const short8*)&sB[cur][ks][rb0];
            short8 b1 = *(const short8*)&sB[cur][ks][rb1];
            acc[0][0] = __builtin_amdgcn_mfma_f32_16x16x32_bf16(a0, b0, acc[0][0], 0, 0, 0);
            acc[0][1] = __builtin_amdgcn_mfma_f32_16x16x32_bf16(a0, b1, acc[0][1], 0, 0, 0);
            acc[1][0] = __builtin_amdgcn_mfma_f32_16x16x32_bf16(a1, b0, acc[1][0], 0, 0, 0);
            acc[1][1] = __builtin_amdgcn_mfma_f32_16x16x32_bf16(a1, b1, acc[1][1], 0, 0, 0);
        }
    }

    const int rq = (lane >> 4) * 4;
    if (isF) {
#pragma unroll
        for (int jj = 0; jj < 2; ++jj) {
            int n = wn + jj * 16 + fr;            // < 64
            float bv = bias[n];
#pragma unroll
            for (int i = 0; i < 2; ++i)
#pragma unroll
                for (int r = 0; r < 4; ++r) {
                    int m = m0 + wm + i * 16 + rq + r;
                    drift[(size_t)m * kH + n] = tanhf(acc[i][jj][r] + bv);
                }
        }
    } else {
#pragma unroll
        for (int jj = 0; jj < 2; ++jj) {
            int n = wn + jj * 16 + fr;
            float bv = bias[n];
            int h = (n0 + wn + jj * 16) >> 4;     // noise col fr, output h
#pragma unroll
            for (int i = 0; i < 2; ++i)
#pragma unroll
                for (int r = 0; r < 4; ++r) {
                    int mr = wm + i * 16 + rq + r;           // row within tile
                    float v = tanhf(acc[i][jj][r] + bv);
                    float p = v * sdb[mr * 16 + fr];
                    p += __shfl_xor(p, 1);
                    p += __shfl_xor(p, 2);
                    p += __shfl_xor(p, 4);
                    p += __shfl_xor(p, 8);
                    if (fr == 0)
                        xdelta[(size_t)(m0 + mr) * kH + h] = p;
                }
        }
    }
}

// ---- final state update (k = T-1) -------------------------------------------
__global__ __launch_bounds__(256) void update_k(float* __restrict__ hist,
                                                const float* __restrict__ drift,
                                                const float* __restrict__ xdelta, int k) {
    int idx = blockIdx.x * 256 + threadIdx.x;
    hist[(size_t)(k + 1) * kBH + idx] =
        hist[(size_t)k * kBH + idx] + drift[idx] + xdelta[idx];
}

// ---- readout ----------------------------------------------------------------
__global__ __launch_bounds__(256) void readout_k(const float* __restrict__ hist,
                                                 const float* __restrict__ rW,
                                                 const float* __restrict__ rb,
                                                 const float* __restrict__ ts,
                                                 float* __restrict__ out) {
    __shared__ float sW[kH * kD];
    __shared__ float sb[kD];
    __shared__ float sts[kT];
    int tid = threadIdx.x;
    sW[tid] = rW[tid];
    sW[tid + 256] = rW[tid + 256];
    if (tid < kD) sb[tid] = rb[tid];
    if (tid < kT) sts[tid] = ts[tid];
    __syncthreads();
    int idx = blockIdx.x * 256 + tid;
    int t = idx & (kT - 1), b = idx >> 6;
    const float* xr = hist + (size_t)t * kBH + (size_t)b * kH;
    float acc[kD];
#pragma unroll
    for (int d = 0; d < kD; ++d) acc[d] = sb[d];
    for (int h = 0; h < kH; ++h) {
        float x = xr[h];
#pragma unroll
        for (int d = 0; d < kD; ++d) acc[d] += x * sW[h * kD + d];
    }
    float* o = out + (size_t)((size_t)b * kT + t) * (1 + kD);
    o[0] = sts[t];
#pragma unroll
    for (int d = 0; d < kD; ++d) o[1 + d] = acc[d];
}

extern "C" void kernel_launch(void* const* d_in, const int* in_sizes, int n_in,
                              void* d_out, int out_size, void* d_ws, size_t ws_size,
                              hipStream_t stream) {
    const float* fW0 = (const float*)d_in[0];  const float* fb0 = (const float*)d_in[1];
    const float* fW1 = (const float*)d_in[2];  const float* fb1 = (const float*)d_in[3];
    const float* fW2 = (const float*)d_in[4];  const float* fb2 = (const float*)d_in[5];
    const float* fW3 = (const float*)d_in[6];  const float* fb3 = (const float*)d_in[7];
    const float* gW0 = (const float*)d_in[8];  const float* gb0 = (const float*)d_in[9];
    const float* gW1 = (const float*)d_in[10]; const float* gb1 = (const float*)d_in[11];
    const float* gW2 = (const float*)d_in[12]; const float* gb2 = (const float*)d_in[13];
    const float* gW3 = (const float*)d_in[14]; const float* gb3 = (const float*)d_in[15];
    const float* rW  = (const float*)d_in[16]; const float* rb  = (const float*)d_in[17];
    const float* ts  = (const float*)d_in[18]; const float* dbt = (const float*)d_in[19];
    float* out = (float*)d_out;

    // workspace carve (all 16B aligned). Total ~47 MB.
    char* p = (char*)d_ws;
    float* hist   = (float*)p;  p += (size_t)kT * kBH * 4;    // 33.55 MB
    float* drift  = (float*)p;  p += (size_t)kBH * 4;         // 0.52 MB
    float* xdelta = (float*)p;  p += (size_t)kBH * 4;         // 0.52 MB
    float* b0c    = (float*)p;  p += 1024 * 4;
    short* txh    = (short*)p;  p += (size_t)kB * kKP * 2;    // 1.5 MB
    short* b1h    = (short*)p;  p += (size_t)kB * 1024 * 2;   // 4 MB
    short* b2h    = (short*)p;  p += (size_t)kB * 1024 * 2;   // 4 MB
    short* W0t    = (short*)p;  p += (size_t)1024 * kKP * 2;  // 0.75 MB
    short* fW1t   = (short*)p;  p += (size_t)512 * 512 * 2;
    short* gW1t   = (short*)p;  p += (size_t)512 * 512 * 2;
    short* fW2t   = (short*)p;  p += (size_t)512 * 512 * 2;
    short* gW2t   = (short*)p;  p += (size_t)512 * 512 * 2;
    short* fW3t   = (short*)p;  p += (size_t)64 * 512 * 2;
    short* gW3t   = (short*)p;  p += (size_t)1024 * 512 * 2;

    auto tgrid = [](int n) { return dim3((n + 255) / 256); };
    transpose_bf16<<<tgrid(kKP * 512), 256, 0, stream>>>(fW0, W0t, kDIN, 512, kKP, 512);
    transpose_bf16<<<tgrid(kKP * 512), 256, 0, stream>>>(gW0, W0t + (size_t)512 * kKP, kDIN, 512, kKP, 512);
    transpose_bf16<<<tgrid(512 * 512), 256, 0, stream>>>(fW1, fW1t, 512, 512, 512, 512);
    transpose_bf16<<<tgrid(512 * 512), 256, 0, stream>>>(gW1, gW1t, 512, 512, 512, 512);
    transpose_bf16<<<tgrid(512 * 512), 256, 0, stream>>>(fW2, fW2t, 512, 512, 512, 512);
    transpose_bf16<<<tgrid(512 * 512), 256, 0, stream>>>(gW2, gW2t, 512, 512, 512, 512);
    transpose_bf16<<<tgrid(512 * 64), 256, 0, stream>>>(fW3, fW3t, 512, 64, 512, 64);
    transpose_bf16<<<tgrid(512 * 1024), 256, 0, stream>>>(gW3, gW3t, 512, 1024, 512, 1024);
    prep_bias<<<dim3(4), 256, 0, stream>>>(fb0, gb0, b0c);
    init_k<<<dim3(kBH / 256), 256, 0, stream>>>(hist, txh);

    for (int k = 0; k < kT - 1; ++k) {
        step_pre<<<dim3(kBH / 256), 256, 0, stream>>>(hist, drift, xdelta, txh, k);

        MArg l1{txh, W0t, b0c, b1h, kKP, kKP, 1024, 1024};
        gemm128<<<dim3(16, 16), 512, 0, stream>>>(l1, l1, 16);

        MArg f2{b1h, fW1t, fb1, b2h, 512, 1024, 1024, 512};
        MArg g2{b1h + 512, gW1t, gb1, b2h + 512, 512, 1024, 1024, 512};
        gemm128<<<dim3(16, 16), 512, 0, stream>>>(f2, g2, 8);

        MArg f3{b2h, fW2t, fb2, b1h, 512, 1024, 1024, 512};
        MArg g3{b2h + 512, gW2t, gb2, b1h + 512, 512, 1024, 1024, 512};
        gemm128<<<dim3(16, 16), 512, 0, stream>>>(f3, g3, 8);

        l4_kernel<<<dim3(16, 17), 512, 0, stream>>>(b1h, fW3t, fb3, gW3t, gb3,
                                                    dbt, drift, xdelta, k);
    }

    update_k<<<dim3(kBH / 256), 256, 0, stream>>>(hist, drift, xdelta, kT - 2);
    readout_k<<<dim3(kB * kT / 256), 256, 0, stream>>>(hist, rW, rb, ts, out);
}